// Round 1
// baseline (2720.698 us; speedup 1.0000x reference)
//
#include <hip/hip_runtime.h>
#include <math.h>

#define BN_EPS 1e-5f

constexpr int B  = 4;
constexpr int C  = 256;
constexpr int HW = 4096;   // 64*64
constexpr int CK = 64;
constexpr int CV = 256;
constexpr int CO = CK + CV;  // 320

// ---------------------------------------------------------------------------
// Kernel 1: K = BN(Wk x + bk), V = Wv x + bv      (1x1 conv == channel GEMM)
// K[b][ck][hw], V[b][cv][hw] into workspace.
// Block: 256 threads -> 256-wide hw tile, 16 output channels, loop c in 32s.
// ---------------------------------------------------------------------------
__global__ __launch_bounds__(256) void kv_kernel(
    const float* __restrict__ x,  const float* __restrict__ Wk, const float* __restrict__ bk,
    const float* __restrict__ gamma, const float* __restrict__ beta,
    const float* __restrict__ mean,  const float* __restrict__ var,
    const float* __restrict__ Wv, const float* __restrict__ bv,
    float* __restrict__ Kbuf, float* __restrict__ Vbuf)
{
    __shared__ float xs[32][256];   // [c][hw]  32 KB
    __shared__ float wls[32][16];   // [ci][coi] 2 KB (coi-contiguous for b128 bcast)

    const int t   = threadIdx.x;
    const int hw0 = blockIdx.x * 256;
    const int co0 = blockIdx.y * 16;
    const int b   = blockIdx.z;

    float acc[16];
#pragma unroll
    for (int i = 0; i < 16; i++) acc[i] = 0.f;

    const float* xb = x + (size_t)b * C * HW;

    for (int c0 = 0; c0 < C; c0 += 32) {
        // stage x chunk: 32 x 256 floats, float4-coalesced
#pragma unroll
        for (int r = 0; r < 8; r++) {
            int q  = r * 256 + t;        // float4 id 0..2047
            int c  = q >> 6;             // 64 float4 per row
            int h4 = (q & 63) * 4;
            *(float4*)&xs[c][h4] = *(const float4*)&xb[(size_t)(c0 + c) * HW + hw0 + h4];
        }
        // stage W chunk: 16 co x 32 c
#pragma unroll
        for (int r = 0; r < 2; r++) {
            int idx = r * 256 + t;       // 0..511
            int coi = idx >> 5;          // 0..15
            int ci  = idx & 31;
            int co  = co0 + coi;
            float w = (co < CK) ? Wk[co * C + c0 + ci]
                                : Wv[(co - CK) * C + c0 + ci];
            wls[ci][coi] = w;
        }
        __syncthreads();

#pragma unroll
        for (int ci = 0; ci < 32; ci++) {
            float xv = xs[ci][t];
#pragma unroll
            for (int q = 0; q < 4; q++) {
                float4 w4 = *(const float4*)&wls[ci][q * 4];
                acc[q * 4 + 0] += w4.x * xv;
                acc[q * 4 + 1] += w4.y * xv;
                acc[q * 4 + 2] += w4.z * xv;
                acc[q * 4 + 3] += w4.w * xv;
            }
        }
        __syncthreads();
    }

    const int hw = hw0 + t;
#pragma unroll
    for (int coi = 0; coi < 16; coi++) {
        int co = co0 + coi;
        if (co < CK) {
            float inv = gamma[co] * rsqrtf(var[co] + BN_EPS);
            float add = beta[co] - mean[co] * inv;
            Kbuf[((size_t)b * CK + co) * HW + hw] = (acc[coi] + bk[co]) * inv + add;
        } else {
            int cv = co - CK;
            Vbuf[((size_t)b * CV + cv) * HW + hw] = acc[coi] + bv[cv];
        }
    }
}

// ---------------------------------------------------------------------------
// Kernel 2: flash-style fused attention.
//   energy[i,j] = sum_ck K[ck,i] K[ck,j];  attn = softmax_j;  out = V attn^T
// One block per (64-row tile, b). 256 threads.
// S phase:  lane = j, wave wv owns rows wv*16..+15 (shuffle-reduced softmax).
// PV phase: lane = i, wave wv owns channels wv*64..+63; O[64] in regs.
// ---------------------------------------------------------------------------
__global__ __launch_bounds__(256) void attn_kernel(
    const float* __restrict__ Kbuf, const float* __restrict__ Vbuf,
    float* __restrict__ out)
{
    extern __shared__ float smem[];
    float* Qs      = smem;                 // 64ck x 64i      (4096)
    float* Ks      = Qs + 64 * 64;         // 64ck x 64j      (4096)
    float* Vs      = Ks + 64 * 64;         // 256c x 64j      (16384)
    float* Pl      = Vs + 256 * 64;        // 64j x 65 (pad)  (4160)
    float* alpha_s = Pl + 64 * 65;         // 64
    float* l_s     = alpha_s + 64;         // 64

    const int t    = threadIdx.x;
    const int lane = t & 63;
    const int wv   = t >> 6;               // 0..3
    const int b    = blockIdx.y;
    const int i0g  = blockIdx.x * 64;      // global row base

    const float* Kb = Kbuf + (size_t)b * CK * HW;
    const float* Vb = Vbuf + (size_t)b * CV * HW;

    // load Q tile (64x64) once, float4-coalesced
#pragma unroll
    for (int r = 0; r < 4; r++) {
        int q  = r * 256 + t;              // float4 id 0..1023
        int ck = q >> 4;                   // 16 float4 per 64-wide row
        int i4 = (q & 15) * 4;
        *(float4*)&Qs[ck * 64 + i4] = *(const float4*)&Kb[(size_t)ck * HW + i0g + i4];
    }

    float O[64];
#pragma unroll
    for (int i = 0; i < 64; i++) O[i] = 0.f;

    float mrow[16], lrow[16];
#pragma unroll
    for (int i = 0; i < 16; i++) { mrow[i] = -1e30f; lrow[i] = 0.f; }

    const int ib0 = wv * 16;               // S-phase row base of this wave
    const int cb  = wv * 64;               // PV-phase channel base

    for (int j0 = 0; j0 < HW; j0 += 64) {
        __syncthreads();                   // prev PV done before tile overwrite
        // stage K tile (64x64) and V tile (256x64)
#pragma unroll
        for (int r = 0; r < 4; r++) {
            int q  = r * 256 + t;
            int ck = q >> 4;
            int j4 = (q & 15) * 4;
            *(float4*)&Ks[ck * 64 + j4] = *(const float4*)&Kb[(size_t)ck * HW + j0 + j4];
        }
#pragma unroll
        for (int r = 0; r < 16; r++) {
            int q  = r * 256 + t;
            int c  = q >> 4;
            int j4 = (q & 15) * 4;
            *(float4*)&Vs[c * 64 + j4] = *(const float4*)&Vb[(size_t)c * HW + j0 + j4];
        }
        __syncthreads();

        // ---- S phase: s[ii] = energy[ib0+ii][lane] ----
        float s[16];
#pragma unroll
        for (int ii = 0; ii < 16; ii++) s[ii] = 0.f;
#pragma unroll 4
        for (int ck = 0; ck < CK; ck++) {
            float kv = Ks[ck * 64 + lane];
#pragma unroll
            for (int q = 0; q < 4; q++) {
                float4 qv = *(const float4*)&Qs[ck * 64 + ib0 + q * 4];
                s[q * 4 + 0] += qv.x * kv;
                s[q * 4 + 1] += qv.y * kv;
                s[q * 4 + 2] += qv.z * kv;
                s[q * 4 + 3] += qv.w * kv;
            }
        }
        // online softmax per row (wave-wide reductions; lanes hold j)
#pragma unroll
        for (int ii = 0; ii < 16; ii++) {
            float v = s[ii];
#pragma unroll
            for (int off = 32; off > 0; off >>= 1)
                v = fmaxf(v, __shfl_xor(v, off, 64));
            float mnew = fmaxf(mrow[ii], v);
            float al   = __expf(mrow[ii] - mnew);
            float p    = __expf(s[ii] - mnew);
            float ps   = p;
#pragma unroll
            for (int off = 32; off > 0; off >>= 1)
                ps += __shfl_xor(ps, off, 64);
            lrow[ii] = lrow[ii] * al + ps;
            mrow[ii] = mnew;
            Pl[lane * 65 + ib0 + ii] = p;              // transposed store, pad=65
            if (lane == 0) alpha_s[ib0 + ii] = al;
        }
        __syncthreads();

        // ---- PV phase: O[cc] for channel cb+cc, row i = lane ----
        float al = alpha_s[lane];
#pragma unroll
        for (int cc = 0; cc < 64; cc++) O[cc] *= al;
#pragma unroll 2
        for (int j = 0; j < 64; j += 4) {
            float p0 = Pl[(j + 0) * 65 + lane];
            float p1 = Pl[(j + 1) * 65 + lane];
            float p2 = Pl[(j + 2) * 65 + lane];
            float p3 = Pl[(j + 3) * 65 + lane];
#pragma unroll
            for (int cc = 0; cc < 64; cc++) {
                float4 v4 = *(const float4*)&Vs[(cb + cc) * 64 + j];  // b128 bcast
                O[cc] += p0 * v4.x + p1 * v4.y + p2 * v4.z + p3 * v4.w;
            }
        }
    }

    // final 1/l normalization + store
#pragma unroll
    for (int ii = 0; ii < 16; ii++)
        if (lane == 0) l_s[ib0 + ii] = lrow[ii];
    __syncthreads();

    float linv = 1.0f / l_s[lane];
    float* ob = out + (size_t)b * CV * HW;
#pragma unroll
    for (int cc = 0; cc < 64; cc++)
        ob[(size_t)(cb + cc) * HW + i0g + lane] = O[cc] * linv;
}

// ---------------------------------------------------------------------------
extern "C" void kernel_launch(void* const* d_in, const int* in_sizes, int n_in,
                              void* d_out, int out_size, void* d_ws, size_t ws_size,
                              hipStream_t stream)
{
    const float* x     = (const float*)d_in[0];
    const float* Wk    = (const float*)d_in[1];
    const float* bk    = (const float*)d_in[2];
    const float* gamma = (const float*)d_in[3];
    const float* beta  = (const float*)d_in[4];
    const float* mean  = (const float*)d_in[5];
    const float* var   = (const float*)d_in[6];
    const float* Wv    = (const float*)d_in[7];
    const float* bv    = (const float*)d_in[8];
    float* out = (float*)d_out;

    float* Kbuf = (float*)d_ws;                          //  4.19 MB
    float* Vbuf = Kbuf + (size_t)B * CK * HW;            // 16.78 MB

    dim3 g1(HW / 256, CO / 16, B);                       // (16,20,4)
    kv_kernel<<<g1, 256, 0, stream>>>(x, Wk, bk, gamma, beta, mean, var, Wv, bv,
                                      Kbuf, Vbuf);

    size_t smem = (size_t)(64 * 64 + 64 * 64 + 256 * 64 + 64 * 65 + 64 + 64) * sizeof(float);
    dim3 g2(HW / 64, B);                                 // (64,4)
    attn_kernel<<<g2, 256, smem, stream>>>(Kbuf, Vbuf, out);
}

// Round 2
// 421.253 us; speedup vs baseline: 6.4586x; 6.4586x over previous
//
#include <hip/hip_runtime.h>
#include <math.h>

#define BN_EPS 1e-5f

constexpr int B  = 4;
constexpr int C  = 256;
constexpr int HW = 4096;   // 64*64
constexpr int CK = 64;
constexpr int CV = 256;
constexpr int COB = 80;    // output channels per kv block (4 blocks cover 320)

typedef short bf16x8 __attribute__((ext_vector_type(8)));
typedef float f32x4  __attribute__((ext_vector_type(4)));

__device__ __forceinline__ ushort f2bf(float f) {
    unsigned u = __float_as_uint(f);
    u += 0x7FFFu + ((u >> 16) & 1u);      // round to nearest even
    return (ushort)(u >> 16);
}

// ---------------------------------------------------------------------------
// Kernel 1: K = BN(Wk x + bk) -> bf16 [b][hw][ck]   (ck contiguous: MFMA frag rows)
//           V = Wv x + bv     -> bf16 [b][cv][hw]   (hw contiguous)
// ---------------------------------------------------------------------------
__global__ __launch_bounds__(256) void kv_kernel(
    const float* __restrict__ x,  const float* __restrict__ Wk, const float* __restrict__ bk,
    const float* __restrict__ gamma, const float* __restrict__ beta,
    const float* __restrict__ mean,  const float* __restrict__ var,
    const float* __restrict__ Wv, const float* __restrict__ bv,
    ushort* __restrict__ Kbuf, ushort* __restrict__ Vbuf)
{
    __shared__ float xs[32][256];     // 32 KB
    __shared__ float wls[32][COB];    // 10 KB

    const int t   = threadIdx.x;
    const int hw0 = blockIdx.x * 256;
    const int co0 = blockIdx.y * COB;
    const int b   = blockIdx.z;

    float acc[COB];
#pragma unroll
    for (int i = 0; i < COB; i++) acc[i] = 0.f;

    const float* xb = x + (size_t)b * C * HW;

    for (int c0 = 0; c0 < C; c0 += 32) {
#pragma unroll
        for (int r = 0; r < 8; r++) {
            int qq = r * 256 + t;
            int c  = qq >> 6;
            int h4 = (qq & 63) * 4;
            *(float4*)&xs[c][h4] = *(const float4*)&xb[(size_t)(c0 + c) * HW + hw0 + h4];
        }
#pragma unroll
        for (int r = 0; r < 10; r++) {            // 2560 = 10*256 weights
            int idx = r * 256 + t;
            int ci  = idx / COB;
            int coi = idx % COB;
            int co  = co0 + coi;
            wls[ci][coi] = (co < CK) ? Wk[co * C + c0 + ci]
                                     : Wv[(co - CK) * C + c0 + ci];
        }
        __syncthreads();

#pragma unroll
        for (int ci = 0; ci < 32; ci++) {
            float xv = xs[ci][t];
#pragma unroll
            for (int qq = 0; qq < COB / 4; qq++) {
                float4 w4 = *(const float4*)&wls[ci][qq * 4];
                acc[qq * 4 + 0] += w4.x * xv;
                acc[qq * 4 + 1] += w4.y * xv;
                acc[qq * 4 + 2] += w4.z * xv;
                acc[qq * 4 + 3] += w4.w * xv;
            }
        }
        __syncthreads();
    }

    const int hw = hw0 + t;
    ushort* Krow = Kbuf + ((size_t)b * HW + hw) * CK;
#pragma unroll
    for (int coi = 0; coi < COB; coi++) {
        int co = co0 + coi;
        float v = acc[coi];
        if (co < CK) {
            float inv = gamma[co] * rsqrtf(var[co] + BN_EPS);
            v = (v + bk[co]) * inv + (beta[co] - mean[co] * inv);
            Krow[co] = f2bf(v);
        } else {
            int cv = co - CK;
            Vbuf[((size_t)b * CV + cv) * HW + hw] = f2bf(v + bv[cv]);
        }
    }
}

// ---------------------------------------------------------------------------
// Kernel 2: MFMA flash attention.  energy = K_i . K_j, softmax_j, out = V attn^T
// Block: 256 thr (4 waves), 64 query rows.  j-tiles of 64.
// S phase : wave w owns i-tile w (16 rows x 64 j), D[i][j] = Q.K  (A=Q, B=K)
// PV phase: wave w owns c-range w*64..+64,  D[c][i] = V.P  (A=V, B=P from LDS)
// Q/K/V frags direct from global (L1/L2: whole K+V = 10.5 MB, L2-resident).
// ---------------------------------------------------------------------------
__global__ __launch_bounds__(256, 1) void attn_kernel(
    const ushort* __restrict__ Kbuf, const ushort* __restrict__ Vbuf,
    float* __restrict__ out)
{
    __shared__ __align__(16) ushort Ps[64][72];   // [i][j], pad 72 (144B rows, 16B-mult)
    __shared__ float alpha_s[64];
    __shared__ float l_s[64];

    const int t    = threadIdx.x;
    const int lane = t & 63;
    const int wv   = t >> 6;          // 0..3
    const int q    = lane >> 4;       // quad 0..3
    const int col  = lane & 15;
    const int b    = blockIdx.y;
    const int i0g  = blockIdx.x * 64;

    const ushort* Kb = Kbuf + (size_t)b * HW * CK;
    const ushort* Vb = Vbuf + (size_t)b * CV * HW;

    // Q A-frags (i-tile = wv), live whole kernel: A[m=i][k=ck]
    bf16x8 qa[2];
#pragma unroll
    for (int k = 0; k < 2; k++)
        qa[k] = *(const bf16x8*)(Kb + (size_t)(i0g + wv * 16 + col) * CK + k * 32 + q * 8);

    f32x4 Oacc[4][4];                 // [mt: c-tile][nt: i-tile]
#pragma unroll
    for (int mt = 0; mt < 4; mt++)
#pragma unroll
        for (int nt = 0; nt < 4; nt++)
            Oacc[mt][nt] = (f32x4){0.f, 0.f, 0.f, 0.f};

    float m_r[4], l_r[4];
#pragma unroll
    for (int r = 0; r < 4; r++) { m_r[r] = -1e30f; l_r[r] = 0.f; }

    const f32x4 zf = (f32x4){0.f, 0.f, 0.f, 0.f};

    for (int j0 = 0; j0 < HW; j0 += 64) {
        // ---- prefetch global frags for this tile ----
        bf16x8 kf[4][2];              // B[k=ck][n=j] from Kbuf[j][ck]
        bf16x8 vf[4][2];              // A[m=c][k=j]  from Vbuf[c][j]
#pragma unroll
        for (int nt = 0; nt < 4; nt++)
#pragma unroll
            for (int k = 0; k < 2; k++)
                kf[nt][k] = *(const bf16x8*)(Kb + (size_t)(j0 + nt * 16 + col) * CK + k * 32 + q * 8);
#pragma unroll
        for (int mt = 0; mt < 4; mt++)
#pragma unroll
            for (int k = 0; k < 2; k++)
                vf[mt][k] = *(const bf16x8*)(Vb + (size_t)(wv * 64 + mt * 16 + col) * HW + j0 + k * 32 + q * 8);

        // ---- S = Q.K : 8 MFMA ----
        f32x4 S[4];
#pragma unroll
        for (int nt = 0; nt < 4; nt++) {
            S[nt] = __builtin_amdgcn_mfma_f32_16x16x32_bf16(qa[0], kf[nt][0], zf, 0, 0, 0);
            S[nt] = __builtin_amdgcn_mfma_f32_16x16x32_bf16(qa[1], kf[nt][1], S[nt], 0, 0, 0);
        }

        // ---- online softmax (rows wv*16+q*4+r, cols = col + nt*16) ----
        float p[4][4];                // [nt][r]
        float alpha[4];
#pragma unroll
        for (int r = 0; r < 4; r++) {
            float mx = fmaxf(fmaxf(S[0][r], S[1][r]), fmaxf(S[2][r], S[3][r]));
#pragma unroll
            for (int off = 1; off <= 8; off <<= 1)
                mx = fmaxf(mx, __shfl_xor(mx, off, 64));
            float mnew = fmaxf(m_r[r], mx);
            alpha[r] = __expf(m_r[r] - mnew);
            m_r[r] = mnew;
            float ps = 0.f;
#pragma unroll
            for (int nt = 0; nt < 4; nt++) {
                p[nt][r] = __expf(S[nt][r] - mnew);
                ps += p[nt][r];
            }
#pragma unroll
            for (int off = 1; off <= 8; off <<= 1)
                ps += __shfl_xor(ps, off, 64);
            l_r[r] = l_r[r] * alpha[r] + ps;
        }

        // partner values for bf16x2 packing (lane ^ 1 holds adjacent column)
        float pr[4][4];
#pragma unroll
        for (int nt = 0; nt < 4; nt++)
#pragma unroll
            for (int r = 0; r < 4; r++)
                pr[nt][r] = __shfl_xor(p[nt][r], 1, 64);

        __syncthreads();   // previous PV's Ps reads complete

        // ---- write P tile (bf16, [i][j]) : even lanes rows r=0,1; odd r=2,3 ----
        {
            const int row0 = wv * 16 + q * 4;
            const int evenl = (lane & 1) == 0;
            const int cb = (col & ~1);
#pragma unroll
            for (int nt = 0; nt < 4; nt++)
#pragma unroll
                for (int rr = 0; rr < 2; rr++) {
                    int r = (evenl ? 0 : 2) + rr;
                    unsigned lo = f2bf(evenl ? p[nt][r] : pr[nt][r]);
                    unsigned hi = f2bf(evenl ? pr[nt][r] : p[nt][r]);
                    *(unsigned*)&Ps[row0 + r][cb + nt * 16] = lo | (hi << 16);
                }
            if (col == 0) {
#pragma unroll
                for (int r = 0; r < 4; r++) alpha_s[row0 + r] = alpha[r];
            }
        }
        __syncthreads();   // Ps + alpha visible to all waves

        // ---- rescale O by alpha (alpha indexed by i = nt*16+col) ----
        float a_n[4];
#pragma unroll
        for (int nt = 0; nt < 4; nt++) a_n[nt] = alpha_s[nt * 16 + col];
#pragma unroll
        for (int mt = 0; mt < 4; mt++)
#pragma unroll
            for (int nt = 0; nt < 4; nt++) {
                Oacc[mt][nt][0] *= a_n[nt];
                Oacc[mt][nt][1] *= a_n[nt];
                Oacc[mt][nt][2] *= a_n[nt];
                Oacc[mt][nt][3] *= a_n[nt];
            }

        // ---- PV: D[c][i] += V.P ----
        bf16x8 pf[4][2];              // B[k=j][n=i] from Ps[i][j]
#pragma unroll
        for (int nt = 0; nt < 4; nt++)
#pragma unroll
            for (int k = 0; k < 2; k++)
                pf[nt][k] = *(const bf16x8*)&Ps[nt * 16 + col][k * 32 + q * 8];
#pragma unroll
        for (int mt = 0; mt < 4; mt++)
#pragma unroll
            for (int nt = 0; nt < 4; nt++) {
                Oacc[mt][nt] = __builtin_amdgcn_mfma_f32_16x16x32_bf16(vf[mt][0], pf[nt][0], Oacc[mt][nt], 0, 0, 0);
                Oacc[mt][nt] = __builtin_amdgcn_mfma_f32_16x16x32_bf16(vf[mt][1], pf[nt][1], Oacc[mt][nt], 0, 0, 0);
            }
    }

    // ---- epilogue: normalize by l, store (i-contiguous, coalesced) ----
    if (col == 0) {
        const int row0 = wv * 16 + q * 4;
#pragma unroll
        for (int r = 0; r < 4; r++) l_s[row0 + r] = l_r[r];
    }
    __syncthreads();

    float linv[4];
#pragma unroll
    for (int nt = 0; nt < 4; nt++) linv[nt] = 1.0f / l_s[nt * 16 + col];

    float* ob = out + (size_t)b * CV * HW;
#pragma unroll
    for (int mt = 0; mt < 4; mt++)
#pragma unroll
        for (int r = 0; r < 4; r++) {
            size_t c = wv * 64 + mt * 16 + q * 4 + r;
#pragma unroll
            for (int nt = 0; nt < 4; nt++)
                ob[c * HW + i0g + nt * 16 + col] = Oacc[mt][nt][r] * linv[nt];
        }
}

// ---------------------------------------------------------------------------
extern "C" void kernel_launch(void* const* d_in, const int* in_sizes, int n_in,
                              void* d_out, int out_size, void* d_ws, size_t ws_size,
                              hipStream_t stream)
{
    const float* x     = (const float*)d_in[0];
    const float* Wk    = (const float*)d_in[1];
    const float* bk    = (const float*)d_in[2];
    const float* gamma = (const float*)d_in[3];
    const float* beta  = (const float*)d_in[4];
    const float* mean  = (const float*)d_in[5];
    const float* var   = (const float*)d_in[6];
    const float* Wv    = (const float*)d_in[7];
    const float* bv    = (const float*)d_in[8];
    float* out = (float*)d_out;

    ushort* Kbuf = (ushort*)d_ws;                        // [B][HW][CK] bf16, 2.1 MB
    ushort* Vbuf = Kbuf + (size_t)B * HW * CK;           // [B][CV][HW] bf16, 8.4 MB

    dim3 g1(HW / 256, 320 / COB, B);                     // (16,4,4)
    kv_kernel<<<g1, 256, 0, stream>>>(x, Wk, bk, gamma, beta, mean, var, Wv, bv,
                                      Kbuf, Vbuf);

    dim3 g2(HW / 64, B);                                 // (64,4)
    attn_kernel<<<g2, 256, 0, stream>>>(Kbuf, Vbuf, out);
}